// Round 1
// baseline (474.313 us; speedup 1.0000x reference)
//
#include <hip/hip_runtime.h>
#include <stdint.h>

// Problem constants
static constexpr int B_   = 8;
static constexpr int QL   = 1024;
static constexpr int SLEN = 2048;
static constexpr int QIN  = 1024;
static constexpr int QKD  = 512;
static constexpr int KVIN = 1024;
static constexpr int VDIM = 512;
static constexpr int OUTD = 1024;

typedef float  f32x4  __attribute__((ext_vector_type(4)));
typedef __bf16 bf16x8 __attribute__((ext_vector_type(8)));
typedef unsigned short u16x8 __attribute__((ext_vector_type(8)));

__device__ __forceinline__ unsigned short f2bf(float f) {
  unsigned int u = __builtin_bit_cast(unsigned int, f);
  return (unsigned short)((u + 0x7FFFu + ((u >> 16) & 1u)) >> 16);
}

// async global->LDS, 16B per lane; LDS dest must be wave-uniform base (HW adds lane*16)
__device__ __forceinline__ void async16(const void* g, void* l) {
  __builtin_amdgcn_global_load_lds(
      (__attribute__((address_space(1))) void*)(uintptr_t)g,
      (__attribute__((address_space(3))) void*)(unsigned int)(uintptr_t)l,
      16, 0, 0);
}

// ---------------------------------------------------------------------------
// Generic 128x128-tile bf16 MFMA GEMM, C[M,N] = A[M,K] * Bt[N,K]^T  (+epilogue)
// EPI: 0 = bf16 out (+bias if non-null)
//      1 = f32 out, mask+scale (score)
//      2 = f32 out (+bias)
//      3 = bf16 out, V-transposed store: vT[row>>11][col][row&2047] (+bias)
// AF32: A operand is fp32 in global (reg-stage + convert); else bf16 via
//       global_load_lds.
// ---------------------------------------------------------------------------
template<int EPI, bool AF32>
__global__ __launch_bounds__(256) void gemm_bt_k(
    const void* __restrict__ Ap, const unsigned short* __restrict__ Btp,
    const float* __restrict__ bias, void* __restrict__ Cp,
    int M, int N, int K,
    long sA, long sB, long sC,
    const int* __restrict__ maskp, float scale)
{
  __shared__ unsigned short tA[128 * 32];
  __shared__ unsigned short tB[128 * 32];

  const int tid  = threadIdx.x;
  const int wave = tid >> 6, lane = tid & 63;
  const int wr = wave >> 1, wc = wave & 1;
  const int fr = lane & 15, fq = lane >> 4;
  const int z = blockIdx.z;
  const int row0 = blockIdx.y * 128, col0 = blockIdx.x * 128;

  const unsigned short* Bt  = Btp + (size_t)z * sB;
  const unsigned short* Abf = (const unsigned short*)Ap + (size_t)z * sA;
  const float*          Af  = (const float*)Ap + (size_t)z * sA;

  f32x4 acc[4][4];
#pragma unroll
  for (int i = 0; i < 4; ++i)
#pragma unroll
    for (int j = 0; j < 4; ++j) acc[i][j] = (f32x4)0.f;

  const int nk = K >> 5;
  for (int kt = 0; kt < nk; ++kt) {
    __syncthreads();  // previous tile fully consumed
    // ---- stage Bt tile [128 n][32 k] via global_load_lds (16B/lane) ----
#pragma unroll
    for (int c = 0; c < 2; ++c) {
      int r = (wave << 5) + (c << 4) + (lane >> 2);
      const unsigned short* g = Bt + (size_t)(col0 + r) * K + (kt << 5) + ((lane & 3) << 3);
      async16(g, &tB[(wave << 10) + (c << 9)]);
    }
    // ---- stage A tile [128 m][32 k] ----
    if constexpr (AF32) {
      int r = tid >> 1, kh = (tid & 1) << 4;
      const float4* s4 = (const float4*)(Af + (size_t)(row0 + r) * K + (kt << 5) + kh);
      float4 f0 = s4[0], f1 = s4[1], f2 = s4[2], f3 = s4[3];
      u16x8 lo, hi;
      lo[0]=f2bf(f0.x); lo[1]=f2bf(f0.y); lo[2]=f2bf(f0.z); lo[3]=f2bf(f0.w);
      lo[4]=f2bf(f1.x); lo[5]=f2bf(f1.y); lo[6]=f2bf(f1.z); lo[7]=f2bf(f1.w);
      hi[0]=f2bf(f2.x); hi[1]=f2bf(f2.y); hi[2]=f2bf(f2.z); hi[3]=f2bf(f2.w);
      hi[4]=f2bf(f3.x); hi[5]=f2bf(f3.y); hi[6]=f2bf(f3.z); hi[7]=f2bf(f3.w);
      *(u16x8*)&tA[r * 32 + kh]     = lo;
      *(u16x8*)&tA[r * 32 + kh + 8] = hi;
    } else {
#pragma unroll
      for (int c = 0; c < 2; ++c) {
        int r = (wave << 5) + (c << 4) + (lane >> 2);
        const unsigned short* g = Abf + (size_t)(row0 + r) * K + (kt << 5) + ((lane & 3) << 3);
        async16(g, &tA[(wave << 10) + (c << 9)]);
      }
    }
    __syncthreads();  // compiler drains vmcnt+lgkmcnt before barrier

    // ---- fragments + MFMA ----
    bf16x8 af[4], bfv[4];
#pragma unroll
    for (int mi = 0; mi < 4; ++mi)
      af[mi] = __builtin_bit_cast(bf16x8,
                 *(const u16x8*)&tA[((wr << 6) + (mi << 4) + fr) * 32 + (fq << 3)]);
#pragma unroll
    for (int ni = 0; ni < 4; ++ni)
      bfv[ni] = __builtin_bit_cast(bf16x8,
                 *(const u16x8*)&tB[((wc << 6) + (ni << 4) + fr) * 32 + (fq << 3)]);
#pragma unroll
    for (int mi = 0; mi < 4; ++mi)
#pragma unroll
      for (int ni = 0; ni < 4; ++ni)
        acc[mi][ni] = __builtin_amdgcn_mfma_f32_16x16x32_bf16(af[mi], bfv[ni], acc[mi][ni], 0, 0, 0);
  }

  // ---- epilogue ----
#pragma unroll
  for (int mi = 0; mi < 4; ++mi) {
#pragma unroll
    for (int ni = 0; ni < 4; ++ni) {
      const int col = col0 + (wc << 6) + (ni << 4) + fr;
      const float bval = (EPI == 1) ? 0.f : (bias ? bias[col] : 0.f);
#pragma unroll
      for (int j = 0; j < 4; ++j) {
        const int row = row0 + (wr << 6) + (mi << 4) + (fq << 2) + j;
        const float v = acc[mi][ni][j];
        if constexpr (EPI == 0) {
          ((unsigned short*)Cp)[(size_t)z * sC + (size_t)row * N + col] = f2bf(v + bval);
        } else if constexpr (EPI == 1) {
          float o = maskp[(size_t)z * SLEN + col] ? v * scale : -1e10f;
          ((float*)Cp)[(size_t)z * sC + (size_t)row * N + col] = o;
        } else if constexpr (EPI == 2) {
          ((float*)Cp)[(size_t)z * sC + (size_t)row * N + col] = v + bval;
        } else {  // EPI == 3: v written transposed per batch: vT[b][n][sl]
          ((unsigned short*)Cp)[((size_t)(row >> 11) * VDIM + col) * SLEN + (row & (SLEN - 1))] =
              f2bf(v + bval);
        }
      }
    }
  }
}

// ---------------------------------------------------------------------------
// Transpose + fp32->bf16 convert: out[c][r] = bf16(in[r][c]); R,C multiples of 64
// ---------------------------------------------------------------------------
__global__ __launch_bounds__(256) void tcvt_k(const float* __restrict__ in, int R, int C,
                                              unsigned short* __restrict__ out)
{
  __shared__ unsigned short t[64][65];
  const int c0 = blockIdx.x << 6, r0 = blockIdx.y << 6;
#pragma unroll
  for (int p = 0; p < 16; ++p) {
    int idx = threadIdx.x + (p << 8);
    int i = idx >> 6, j = idx & 63;
    t[i][j] = f2bf(in[(size_t)(r0 + i) * C + c0 + j]);
  }
  __syncthreads();
#pragma unroll
  for (int p = 0; p < 16; ++p) {
    int idx = threadIdx.x + (p << 8);
    int jj = idx >> 6, ii = idx & 63;
    out[(size_t)(c0 + jj) * R + r0 + ii] = t[ii][jj];
  }
}

// ---------------------------------------------------------------------------
// In-place row softmax over rows of 2048 fp32 (one block per row)
// ---------------------------------------------------------------------------
__global__ __launch_bounds__(256) void softmax_k(float* __restrict__ p)
{
  __shared__ float red[8];
  const size_t base = (size_t)blockIdx.x * SLEN;
  const int t = threadIdx.x;
  float4* p4 = (float4*)(p + base);
  float4 a = p4[t * 2], b = p4[t * 2 + 1];

  float m = fmaxf(fmaxf(fmaxf(a.x, a.y), fmaxf(a.z, a.w)),
                  fmaxf(fmaxf(b.x, b.y), fmaxf(b.z, b.w)));
#pragma unroll
  for (int off = 32; off >= 1; off >>= 1) m = fmaxf(m, __shfl_xor(m, off));
  const int wave = t >> 6, lane = t & 63;
  if (lane == 0) red[wave] = m;
  __syncthreads();
  m = fmaxf(fmaxf(red[0], red[1]), fmaxf(red[2], red[3]));

  a.x = __expf(a.x - m); a.y = __expf(a.y - m); a.z = __expf(a.z - m); a.w = __expf(a.w - m);
  b.x = __expf(b.x - m); b.y = __expf(b.y - m); b.z = __expf(b.z - m); b.w = __expf(b.w - m);
  float sum = a.x + a.y + a.z + a.w + b.x + b.y + b.z + b.w;
#pragma unroll
  for (int off = 32; off >= 1; off >>= 1) sum += __shfl_xor(sum, off);
  if (lane == 0) red[4 + wave] = sum;
  __syncthreads();
  const float inv = 1.f / (red[4] + red[5] + red[6] + red[7]);

  a.x *= inv; a.y *= inv; a.z *= inv; a.w *= inv;
  b.x *= inv; b.y *= inv; b.z *= inv; b.w *= inv;
  p4[t * 2] = a; p4[t * 2 + 1] = b;
}

// ---------------------------------------------------------------------------
extern "C" void kernel_launch(void* const* d_in, const int* in_sizes, int n_in,
                              void* d_out, int out_size, void* d_ws, size_t ws_size,
                              hipStream_t stream)
{
  const float* q  = (const float*)d_in[0];
  const float* s  = (const float*)d_in[1];
  const int* mask = (const int*)d_in[2];
  const float* Wq = (const float*)d_in[3];
  const float* bq = (const float*)d_in[4];
  const float* Wk = (const float*)d_in[5];
  const float* bk = (const float*)d_in[6];
  const float* Wv = (const float*)d_in[7];
  const float* bv = (const float*)d_in[8];
  const float* Wo = (const float*)d_in[9];
  const float* bo = (const float*)d_in[10];

  char* ws = (char*)d_ws;
  unsigned short* WqT = (unsigned short*)(ws + ((size_t)0 << 20));   // [512][1024]  1 MB
  unsigned short* WkT = (unsigned short*)(ws + ((size_t)1 << 20));   // [512][1024]  1 MB
  unsigned short* WvT = (unsigned short*)(ws + ((size_t)2 << 20));   // [512][1024]  1 MB
  unsigned short* WoT = (unsigned short*)(ws + ((size_t)3 << 20));   // [1024][512]  1 MB
  unsigned short* qp  = (unsigned short*)(ws + ((size_t)4 << 20));   // [8192][512]  8 MB
  unsigned short* kb  = (unsigned short*)(ws + ((size_t)12 << 20));  // [16384][512] 16 MB
  unsigned short* vT  = (unsigned short*)(ws + ((size_t)28 << 20));  // [8][512][2048] 16 MB
  unsigned short* ao  = (unsigned short*)(ws + ((size_t)44 << 20));  // [8192][512]  8 MB

  float* attn_w = (float*)d_out;                              // [8][1024][2048]
  float* attn_o = (float*)d_out + (size_t)B_ * QL * SLEN;     // [8][1024][1024]

  // 1) weights -> transposed bf16
  tcvt_k<<<dim3(QKD / 64, QIN / 64),  256, 0, stream>>>(Wq, QIN,  QKD,  WqT);
  tcvt_k<<<dim3(QKD / 64, KVIN / 64), 256, 0, stream>>>(Wk, KVIN, QKD,  WkT);
  tcvt_k<<<dim3(VDIM / 64, KVIN / 64),256, 0, stream>>>(Wv, KVIN, VDIM, WvT);
  tcvt_k<<<dim3(OUTD / 64, VDIM / 64),256, 0, stream>>>(Wo, VDIM, OUTD, WoT);

  // 2) projections (fp32 A, bf16 weights)
  gemm_bt_k<0, true><<<dim3(QKD / 128, (B_ * QL) / 128), 256, 0, stream>>>(
      q, WqT, bq, qp, B_ * QL, QKD, QIN, 0, 0, 0, nullptr, 0.f);
  gemm_bt_k<0, true><<<dim3(QKD / 128, (B_ * SLEN) / 128), 256, 0, stream>>>(
      s, WkT, bk, kb, B_ * SLEN, QKD, KVIN, 0, 0, 0, nullptr, 0.f);
  gemm_bt_k<3, true><<<dim3(VDIM / 128, (B_ * SLEN) / 128), 256, 0, stream>>>(
      s, WvT, bv, vT, B_ * SLEN, VDIM, KVIN, 0, 0, 0, nullptr, 0.f);

  // 3) scores = qp . k^T * scale, masked -> fp32 attn_w region
  gemm_bt_k<1, false><<<dim3(SLEN / 128, QL / 128, B_), 256, 0, stream>>>(
      qp, kb, nullptr, attn_w, QL, SLEN, QKD,
      (long)QL * QKD, (long)SLEN * QKD, (long)QL * SLEN, mask, 0.044194173824159216f);

  // 4) row softmax in place
  softmax_k<<<B_ * QL, 256, 0, stream>>>(attn_w);

  // 5) PV: attn_w (fp32, re-staged as bf16) @ v  -> bf16 ao
  gemm_bt_k<0, true><<<dim3(VDIM / 128, QL / 128, B_), 256, 0, stream>>>(
      attn_w, vT, nullptr, ao, QL, VDIM, SLEN,
      (long)QL * SLEN, (long)VDIM * SLEN, (long)QL * VDIM, nullptr, 0.f);

  // 6) out = ao @ Wo + bo -> fp32
  gemm_bt_k<2, false><<<dim3(OUTD / 128, (B_ * QL) / 128), 256, 0, stream>>>(
      ao, WoT, bo, attn_o, B_ * QL, OUTD, VDIM, 0, 0, 0, nullptr, 0.f);
}

// Round 2
// 424.864 us; speedup vs baseline: 1.1164x; 1.1164x over previous
//
#include <hip/hip_runtime.h>
#include <stdint.h>

// Problem constants
static constexpr int B_   = 8;
static constexpr int QL   = 1024;
static constexpr int SLEN = 2048;
static constexpr int QIN  = 1024;
static constexpr int QKD  = 512;
static constexpr int KVIN = 1024;
static constexpr int VDIM = 512;
static constexpr int OUTD = 1024;

typedef float  f32x4  __attribute__((ext_vector_type(4)));
typedef __bf16 bf16x8 __attribute__((ext_vector_type(8)));
typedef unsigned short u16x8 __attribute__((ext_vector_type(8)));

__device__ __forceinline__ unsigned short f2bf(float f) {
  unsigned int u = __builtin_bit_cast(unsigned int, f);
  return (unsigned short)((u + 0x7FFFu + ((u >> 16) & 1u)) >> 16);
}

// async global->LDS, 16B per lane; LDS dest is wave-uniform base (HW adds lane*16)
__device__ __forceinline__ void async16(const void* g, void* l) {
  __builtin_amdgcn_global_load_lds(
      (__attribute__((address_space(1))) void*)(uintptr_t)g,
      (__attribute__((address_space(3))) void*)(unsigned int)(uintptr_t)l,
      16, 0, 0);
}

// ---------------------------------------------------------------------------
// 128x128-tile bf16 MFMA GEMM, C[M,N] = A[M,K] * Bt[N,K]^T  (+epilogue)
// Pure-bf16 operands, both staged via global_load_lds(16B).
// EPI: 0 = bf16 out (+bias if non-null)
//      1 = f32 out, mask+scale (score)
//      2 = f32 out (+bias)
// Bijective XCD swizzle (nwg multiple of 8 for all launches here).
// ---------------------------------------------------------------------------
template<int EPI>
__global__ __launch_bounds__(256) void gemm_bt_k(
    const unsigned short* __restrict__ Ap, const unsigned short* __restrict__ Btp,
    const float* __restrict__ bias, void* __restrict__ Cp,
    int N, int K, long sA, long sB, long sC,
    const int* __restrict__ maskp, float scale)
{
  __shared__ unsigned short tA[128 * 32];
  __shared__ unsigned short tB[128 * 32];

  // ---- XCD-aware block swizzle: XCD x processes a contiguous tile chunk ----
  const unsigned gx = gridDim.x, gy = gridDim.y;
  const unsigned nwg = gx * gy * gridDim.z;
  const unsigned orig = blockIdx.x + gx * (blockIdx.y + gy * blockIdx.z);
  const unsigned swz = (orig & 7) * (nwg >> 3) + (orig >> 3);
  const unsigned bx = swz % gx;
  const unsigned rem = swz / gx;
  const unsigned by = rem % gy;
  const unsigned z  = rem / gy;

  const int tid  = threadIdx.x;
  const int wave = tid >> 6, lane = tid & 63;
  const int wr = wave >> 1, wc = wave & 1;
  const int fr = lane & 15, fq = lane >> 4;
  const int row0 = by * 128, col0 = bx * 128;

  const unsigned short* A  = Ap  + (size_t)z * sA;
  const unsigned short* Bt = Btp + (size_t)z * sB;

  f32x4 acc[4][4];
#pragma unroll
  for (int i = 0; i < 4; ++i)
#pragma unroll
    for (int j = 0; j < 4; ++j) acc[i][j] = (f32x4)0.f;

  const int r_st  = (wave << 5) + (lane >> 2);        // staging row within tile (+16 for c=1)
  const int k_off = (lane & 3) << 3;                  // staging k element offset

  const int nk = K >> 5;
  for (int kt = 0; kt < nk; ++kt) {
    __syncthreads();  // previous tile fully consumed
    const int kbase = kt << 5;
#pragma unroll
    for (int c = 0; c < 2; ++c) {
      const int r = r_st + (c << 4);
      async16(Bt + (size_t)(col0 + r) * K + kbase + k_off, &tB[(wave << 10) + (c << 9)]);
      async16(A  + (size_t)(row0 + r) * K + kbase + k_off, &tA[(wave << 10) + (c << 9)]);
    }
    __syncthreads();  // compiler drains vmcnt before barrier

    bf16x8 af[4], bfv[4];
#pragma unroll
    for (int mi = 0; mi < 4; ++mi)
      af[mi] = __builtin_bit_cast(bf16x8,
                 *(const u16x8*)&tA[((wr << 6) + (mi << 4) + fr) * 32 + (fq << 3)]);
#pragma unroll
    for (int ni = 0; ni < 4; ++ni)
      bfv[ni] = __builtin_bit_cast(bf16x8,
                 *(const u16x8*)&tB[((wc << 6) + (ni << 4) + fr) * 32 + (fq << 3)]);
#pragma unroll
    for (int mi = 0; mi < 4; ++mi)
#pragma unroll
      for (int ni = 0; ni < 4; ++ni)
        acc[mi][ni] = __builtin_amdgcn_mfma_f32_16x16x32_bf16(af[mi], bfv[ni], acc[mi][ni], 0, 0, 0);
  }

  // ---- epilogue ----
#pragma unroll
  for (int mi = 0; mi < 4; ++mi) {
#pragma unroll
    for (int ni = 0; ni < 4; ++ni) {
      const int col = col0 + (wc << 6) + (ni << 4) + fr;
      const float bval = (EPI == 1) ? 0.f : (bias ? bias[col] : 0.f);
#pragma unroll
      for (int j = 0; j < 4; ++j) {
        const int row = row0 + (wr << 6) + (mi << 4) + (fq << 2) + j;
        const float v = acc[mi][ni][j];
        if constexpr (EPI == 0) {
          ((unsigned short*)Cp)[(size_t)z * sC + (size_t)row * N + col] = f2bf(v + bval);
        } else if constexpr (EPI == 1) {
          float o = maskp[(size_t)z * SLEN + col] ? v * scale : -1e10f;
          ((float*)Cp)[(size_t)z * sC + (size_t)row * N + col] = o;
        } else {
          ((float*)Cp)[(size_t)z * sC + (size_t)row * N + col] = v + bval;
        }
      }
    }
  }
}

// ---------------------------------------------------------------------------
// fp32 -> bf16 streaming convert (8 elems/thread)
// ---------------------------------------------------------------------------
__global__ __launch_bounds__(256) void cvt_k(const float* __restrict__ in,
                                             unsigned short* __restrict__ out)
{
  const size_t i = ((size_t)blockIdx.x * 256 + threadIdx.x) * 8;
  float4 a = *(const float4*)(in + i), b = *(const float4*)(in + i + 4);
  u16x8 o;
  o[0]=f2bf(a.x); o[1]=f2bf(a.y); o[2]=f2bf(a.z); o[3]=f2bf(a.w);
  o[4]=f2bf(b.x); o[5]=f2bf(b.y); o[6]=f2bf(b.z); o[7]=f2bf(b.w);
  *(u16x8*)(out + i) = o;
}

// ---------------------------------------------------------------------------
// Weight transpose + fp32->bf16: out[c][r] = bf16(in[r][c]); R,C multiples of 64
// ---------------------------------------------------------------------------
__global__ __launch_bounds__(256) void tcvt_k(const float* __restrict__ in, int R, int C,
                                              unsigned short* __restrict__ out)
{
  __shared__ unsigned short t[64][65];
  const int c0 = blockIdx.x << 6, r0 = blockIdx.y << 6;
#pragma unroll
  for (int p = 0; p < 16; ++p) {
    int idx = threadIdx.x + (p << 8);
    int i = idx >> 6, j = idx & 63;
    t[i][j] = f2bf(in[(size_t)(r0 + i) * C + c0 + j]);
  }
  __syncthreads();
#pragma unroll
  for (int p = 0; p < 16; ++p) {
    int idx = threadIdx.x + (p << 8);
    int jj = idx >> 6, ii = idx & 63;
    out[(size_t)(c0 + jj) * R + r0 + ii] = t[ii][jj];
  }
}

// ---------------------------------------------------------------------------
// bf16 transpose per batch: v[b][sl][vd] -> vT[b][vd][sl], 64x64 LDS tiles
// ---------------------------------------------------------------------------
__global__ __launch_bounds__(256) void vtrans_k(const unsigned short* __restrict__ v,
                                                unsigned short* __restrict__ vt)
{
  __shared__ unsigned short t[64][72];   // row stride 144B: keeps 16B vector alignment
  const int b  = blockIdx.z;
  const int v0 = blockIdx.x << 6;        // vd tile base
  const int s0 = blockIdx.y << 6;        // sl tile base
  const unsigned short* src = v + ((size_t)b * SLEN + s0) * VDIM + v0;
#pragma unroll
  for (int p = 0; p < 2; ++p) {
    int idx = threadIdx.x + (p << 8);
    int i = idx >> 3, j8 = (idx & 7) << 3;
    *(u16x8*)&t[i][j8] = *(const u16x8*)&src[(size_t)i * VDIM + j8];
  }
  __syncthreads();
  unsigned short* dst = vt + ((size_t)b * VDIM + v0) * SLEN + s0;
#pragma unroll
  for (int p = 0; p < 2; ++p) {
    int idx = threadIdx.x + (p << 8);
    int jj = idx >> 3, i8 = (idx & 7) << 3;
    u16x8 o;
#pragma unroll
    for (int e = 0; e < 8; ++e) o[e] = t[i8 + e][jj];
    *(u16x8*)&dst[(size_t)jj * SLEN + i8] = o;
  }
}

// ---------------------------------------------------------------------------
// In-place row softmax over rows of 2048 fp32 + bf16 copy (one block per row)
// ---------------------------------------------------------------------------
__global__ __launch_bounds__(256) void softmax_k(float* __restrict__ p,
                                                 unsigned short* __restrict__ pb)
{
  __shared__ float red[8];
  const size_t base = (size_t)blockIdx.x * SLEN;
  const int t = threadIdx.x;
  float4* p4 = (float4*)(p + base);
  float4 a = p4[t * 2], b = p4[t * 2 + 1];

  float m = fmaxf(fmaxf(fmaxf(a.x, a.y), fmaxf(a.z, a.w)),
                  fmaxf(fmaxf(b.x, b.y), fmaxf(b.z, b.w)));
#pragma unroll
  for (int off = 32; off >= 1; off >>= 1) m = fmaxf(m, __shfl_xor(m, off));
  const int wave = t >> 6, lane = t & 63;
  if (lane == 0) red[wave] = m;
  __syncthreads();
  m = fmaxf(fmaxf(red[0], red[1]), fmaxf(red[2], red[3]));

  a.x = __expf(a.x - m); a.y = __expf(a.y - m); a.z = __expf(a.z - m); a.w = __expf(a.w - m);
  b.x = __expf(b.x - m); b.y = __expf(b.y - m); b.z = __expf(b.z - m); b.w = __expf(b.w - m);
  float sum = a.x + a.y + a.z + a.w + b.x + b.y + b.z + b.w;
#pragma unroll
  for (int off = 32; off >= 1; off >>= 1) sum += __shfl_xor(sum, off);
  if (lane == 0) red[4 + wave] = sum;
  __syncthreads();
  const float inv = 1.f / (red[4] + red[5] + red[6] + red[7]);

  a.x *= inv; a.y *= inv; a.z *= inv; a.w *= inv;
  b.x *= inv; b.y *= inv; b.z *= inv; b.w *= inv;
  p4[t * 2] = a; p4[t * 2 + 1] = b;

  u16x8 o;
  o[0]=f2bf(a.x); o[1]=f2bf(a.y); o[2]=f2bf(a.z); o[3]=f2bf(a.w);
  o[4]=f2bf(b.x); o[5]=f2bf(b.y); o[6]=f2bf(b.z); o[7]=f2bf(b.w);
  *(u16x8*)(pb + base + (size_t)t * 8) = o;
}

// ---------------------------------------------------------------------------
extern "C" void kernel_launch(void* const* d_in, const int* in_sizes, int n_in,
                              void* d_out, int out_size, void* d_ws, size_t ws_size,
                              hipStream_t stream)
{
  const float* q  = (const float*)d_in[0];
  const float* s  = (const float*)d_in[1];
  const int* mask = (const int*)d_in[2];
  const float* Wq = (const float*)d_in[3];
  const float* bq = (const float*)d_in[4];
  const float* Wk = (const float*)d_in[5];
  const float* bk = (const float*)d_in[6];
  const float* Wv = (const float*)d_in[7];
  const float* bv = (const float*)d_in[8];
  const float* Wo = (const float*)d_in[9];
  const float* bo = (const float*)d_in[10];

  // Workspace layout (92 MB peak, buffers reused across the serial stream):
  char* ws = (char*)d_ws;
  unsigned short* WqT = (unsigned short*)(ws + ((size_t)0  << 20));  // [512][1024]   1 MB
  unsigned short* WkT = (unsigned short*)(ws + ((size_t)1  << 20));  // [512][1024]   1 MB
  unsigned short* WvT = (unsigned short*)(ws + ((size_t)2  << 20));  // [512][1024]   1 MB
  unsigned short* WoT = (unsigned short*)(ws + ((size_t)3  << 20));  // [1024][512]   1 MB
  unsigned short* qbf = (unsigned short*)(ws + ((size_t)4  << 20));  // [8192][1024] 16 MB
  unsigned short* vbf = qbf;                                         //  reuse after q-proj
  unsigned short* sbf = (unsigned short*)(ws + ((size_t)20 << 20));  // [16384][1024] 32 MB
  unsigned short* pw  = sbf;                                         //  reuse after v-proj
  unsigned short* qp  = (unsigned short*)(ws + ((size_t)52 << 20));  // [8192][512]   8 MB
  unsigned short* ao  = qp;                                          //  reuse after score
  unsigned short* kb  = (unsigned short*)(ws + ((size_t)60 << 20));  // [16384][512] 16 MB
  unsigned short* vT  = (unsigned short*)(ws + ((size_t)76 << 20));  // [8][512][2048] 16 MB

  float* attn_w = (float*)d_out;                              // [8][1024][2048]
  float* attn_o = (float*)d_out + (size_t)B_ * QL * SLEN;     // [8][1024][1024]

  // 1) activations + weights -> bf16
  cvt_k<<<(B_ * QL * QIN) / (256 * 8), 256, 0, stream>>>(q, qbf);
  cvt_k<<<(B_ * SLEN * KVIN) / (256 * 8), 256, 0, stream>>>(s, sbf);
  tcvt_k<<<dim3(QKD / 64, QIN / 64),   256, 0, stream>>>(Wq, QIN,  QKD,  WqT);
  tcvt_k<<<dim3(QKD / 64, KVIN / 64),  256, 0, stream>>>(Wk, KVIN, QKD,  WkT);
  tcvt_k<<<dim3(VDIM / 64, KVIN / 64), 256, 0, stream>>>(Wv, KVIN, VDIM, WvT);
  tcvt_k<<<dim3(OUTD / 64, VDIM / 64), 256, 0, stream>>>(Wo, VDIM, OUTD, WoT);

  // 2) projections (all pure-bf16)
  gemm_bt_k<0><<<dim3(QKD / 128, (B_ * QL) / 128), 256, 0, stream>>>(
      qbf, WqT, bq, qp, QKD, QIN, 0, 0, 0, nullptr, 0.f);
  gemm_bt_k<0><<<dim3(QKD / 128, (B_ * SLEN) / 128), 256, 0, stream>>>(
      sbf, WkT, bk, kb, QKD, KVIN, 0, 0, 0, nullptr, 0.f);
  gemm_bt_k<0><<<dim3(VDIM / 128, (B_ * SLEN) / 128), 256, 0, stream>>>(
      sbf, WvT, bv, vbf, VDIM, KVIN, 0, 0, 0, nullptr, 0.f);   // v overwrites qbf region

  // 3) v -> vT (coalesced LDS transpose)
  vtrans_k<<<dim3(VDIM / 64, SLEN / 64, B_), 256, 0, stream>>>(vbf, vT);

  // 4) scores = qp . k^T * scale, masked -> fp32 attn_w region
  gemm_bt_k<1><<<dim3(SLEN / 128, QL / 128, B_), 256, 0, stream>>>(
      qp, kb, nullptr, attn_w, SLEN, QKD,
      (long)QL * QKD, (long)SLEN * QKD, (long)QL * SLEN, mask, 0.044194173824159216f);

  // 5) row softmax in place + bf16 copy (pw overwrites sbf region)
  softmax_k<<<B_ * QL, 256, 0, stream>>>(attn_w, pw);

  // 6) PV: pw @ vT^T -> bf16 ao (ao overwrites qp region)
  gemm_bt_k<0><<<dim3(VDIM / 128, QL / 128, B_), 256, 0, stream>>>(
      pw, vT, nullptr, ao, VDIM, SLEN,
      (long)QL * SLEN, (long)VDIM * SLEN, (long)QL * VDIM, nullptr, 0.f);

  // 7) out = ao @ Wo + bo -> fp32
  gemm_bt_k<2><<<dim3(OUTD / 128, (B_ * QL) / 128), 256, 0, stream>>>(
      ao, WoT, bo, attn_o, OUTD, VDIM, 0, 0, 0, nullptr, 0.f);
}

// Round 4
// 373.188 us; speedup vs baseline: 1.2710x; 1.1385x over previous
//
#include <hip/hip_runtime.h>
#include <stdint.h>

// Problem constants
static constexpr int B_   = 8;
static constexpr int QL   = 1024;
static constexpr int SLEN = 2048;
static constexpr int QIN  = 1024;
static constexpr int QKD  = 512;
static constexpr int KVIN = 1024;
static constexpr int VDIM = 512;
static constexpr int OUTD = 1024;

typedef float  f32x4  __attribute__((ext_vector_type(4)));
typedef __bf16 bf16x8 __attribute__((ext_vector_type(8)));
typedef unsigned short u16x8 __attribute__((ext_vector_type(8)));

__device__ __forceinline__ unsigned short f2bf(float f) {
  unsigned int u = __builtin_bit_cast(unsigned int, f);
  return (unsigned short)((u + 0x7FFFu + ((u >> 16) & 1u)) >> 16);
}
__device__ __forceinline__ float bf2f(unsigned short h) {
  return __builtin_bit_cast(float, (unsigned int)h << 16);
}

// async global->LDS, 16B per lane; LDS dest is wave-uniform base (HW adds lane*16)
__device__ __forceinline__ void async16(const void* g, void* l) {
  __builtin_amdgcn_global_load_lds(
      (__attribute__((address_space(1))) void*)(uintptr_t)g,
      (__attribute__((address_space(3))) void*)(unsigned int)(uintptr_t)l,
      16, 0, 0);
}

// ---------------------------------------------------------------------------
// 128x128-tile bf16 MFMA GEMM, C[M,N] = A[M,K] * Bt[N,K]^T  (+epilogue)
// BK=64, double-buffered LDS (64 KB), stage-ahead 2-phase schedule:
//   prologue STAGE(t=0); barrier
//   loop: STAGE(t+1) ; ds_read+MFMA(t) ; __syncthreads (drains vmcnt) ; flip
// EPI: 0 = bf16 out (+bias)   1 = bf16 out, mask+scale (score)
//      2 = f32 out (+bias)
// Bijective XCD swizzle (all grids here are multiples of 8 blocks).
// ---------------------------------------------------------------------------
template<int EPI>
__global__ __launch_bounds__(256) void gemm_bt_k(
    const unsigned short* __restrict__ Ap, const unsigned short* __restrict__ Btp,
    const float* __restrict__ bias, void* __restrict__ Cp,
    int K, int ldA, int ldB, int ldC,
    long sA, long sB, long sC,
    const int* __restrict__ maskp, float scale)
{
  __shared__ unsigned short lds[4][128 * 64];   // A0,B0,A1,B1 — 64 KB

  // ---- XCD-aware block swizzle ----
  const unsigned gx = gridDim.x, gy = gridDim.y;
  const unsigned nwg = gx * gy * gridDim.z;
  const unsigned orig = blockIdx.x + gx * (blockIdx.y + gy * blockIdx.z);
  const unsigned swz = (orig & 7) * (nwg >> 3) + (orig >> 3);
  const unsigned bx = swz % gx;
  const unsigned rem = swz / gx;
  const unsigned by = rem % gy;
  const unsigned z  = rem / gy;

  const int tid  = threadIdx.x;
  const int wave = tid >> 6, lane = tid & 63;
  const int wr = wave >> 1, wc = wave & 1;
  const int fr = lane & 15, fq = lane >> 4;
  const int row0 = by * 128, col0 = bx * 128;

  const unsigned short* A  = Ap  + (size_t)z * sA;
  const unsigned short* Bt = Btp + (size_t)z * sB;

  f32x4 acc[4][4];
#pragma unroll
  for (int i = 0; i < 4; ++i)
#pragma unroll
    for (int j = 0; j < 4; ++j) acc[i][j] = (f32x4)0.f;

  // stage one [128 rows][64 k] tile: 4 rounds x (256 thr x 16B)
  const int s_r   = tid >> 3;           // 0..31 row-in-round
  const int s_k   = (tid & 7) << 3;     // k elem offset
  const int s_lds = (wave << 9);        // wave-uniform elems base within round
  auto stage = [&](const unsigned short* G, int ld, int g0, int kbase,
                   unsigned short* buf) {
#pragma unroll
    for (int c = 0; c < 4; ++c) {
      async16(G + (size_t)(g0 + (c << 5) + s_r) * ld + kbase + s_k,
              buf + (c << 11) + s_lds);
    }
  };

  const int nk = K >> 6;
  stage(A,  ldA, row0, 0, lds[0]);
  stage(Bt, ldB, col0, 0, lds[1]);
  __syncthreads();

  int cur = 0;
  for (int kt = 0; kt < nk; ++kt) {
    if (kt + 1 < nk) {   // issue next tile's loads BEFORE computing current
      const int kb2 = (kt + 1) << 6;
      stage(A,  ldA, row0, kb2, lds[((cur ^ 1) << 1)]);
      stage(Bt, ldB, col0, kb2, lds[((cur ^ 1) << 1) | 1]);
    }
    const unsigned short* tAc = lds[(cur << 1)];
    const unsigned short* tBc = lds[(cur << 1) | 1];

    bf16x8 af[2][4], bfv[2][4];
#pragma unroll
    for (int ks = 0; ks < 2; ++ks) {
#pragma unroll
      for (int mi = 0; mi < 4; ++mi)
        af[ks][mi] = __builtin_bit_cast(bf16x8,
            *(const u16x8*)&tAc[((wr << 6) + (mi << 4) + fr) * 64 + (ks << 5) + (fq << 3)]);
#pragma unroll
      for (int ni = 0; ni < 4; ++ni)
        bfv[ks][ni] = __builtin_bit_cast(bf16x8,
            *(const u16x8*)&tBc[((wc << 6) + (ni << 4) + fr) * 64 + (ks << 5) + (fq << 3)]);
    }
#pragma unroll
    for (int mi = 0; mi < 4; ++mi)
#pragma unroll
      for (int ni = 0; ni < 4; ++ni) {
        acc[mi][ni] = __builtin_amdgcn_mfma_f32_16x16x32_bf16(af[0][mi], bfv[0][ni], acc[mi][ni], 0, 0, 0);
        acc[mi][ni] = __builtin_amdgcn_mfma_f32_16x16x32_bf16(af[1][mi], bfv[1][ni], acc[mi][ni], 0, 0, 0);
      }
    __syncthreads();   // drains vmcnt (next tile landed) + frees cur buffer
    cur ^= 1;
  }

  // ---- epilogue ----
#pragma unroll
  for (int mi = 0; mi < 4; ++mi) {
#pragma unroll
    for (int ni = 0; ni < 4; ++ni) {
      const int col = col0 + (wc << 6) + (ni << 4) + fr;
      const float bval = (EPI == 1) ? 0.f : (bias ? bias[col] : 0.f);
#pragma unroll
      for (int j = 0; j < 4; ++j) {
        const int row = row0 + (wr << 6) + (mi << 4) + (fq << 2) + j;
        const float v = acc[mi][ni][j];
        if constexpr (EPI == 0) {
          ((unsigned short*)Cp)[(size_t)z * sC + (size_t)row * ldC + col] = f2bf(v + bval);
        } else if constexpr (EPI == 1) {
          float o = maskp[(size_t)z * SLEN + col] ? v * scale : -1e10f;
          ((unsigned short*)Cp)[(size_t)z * sC + (size_t)row * ldC + col] = f2bf(o);
        } else {
          ((float*)Cp)[(size_t)z * sC + (size_t)row * ldC + col] = v + bval;
        }
      }
    }
  }
}

// ---------------------------------------------------------------------------
// fp32 -> bf16 streaming convert (8 elems/thread)
// ---------------------------------------------------------------------------
__global__ __launch_bounds__(256) void cvt_k(const float* __restrict__ in,
                                             unsigned short* __restrict__ out)
{
  const size_t i = ((size_t)blockIdx.x * 256 + threadIdx.x) * 8;
  float4 a = *(const float4*)(in + i), b = *(const float4*)(in + i + 4);
  u16x8 o;
  o[0]=f2bf(a.x); o[1]=f2bf(a.y); o[2]=f2bf(a.z); o[3]=f2bf(a.w);
  o[4]=f2bf(b.x); o[5]=f2bf(b.y); o[6]=f2bf(b.z); o[7]=f2bf(b.w);
  *(u16x8*)(out + i) = o;
}

// ---------------------------------------------------------------------------
// Weight transpose + fp32->bf16: out[c][r] = bf16(in[r][c]); R,C multiples of 64
// ---------------------------------------------------------------------------
__global__ __launch_bounds__(256) void tcvt_k(const float* __restrict__ in, int R, int C,
                                              unsigned short* __restrict__ out)
{
  __shared__ unsigned short t[64][65];
  const int c0 = blockIdx.x << 6, r0 = blockIdx.y << 6;
#pragma unroll
  for (int p = 0; p < 16; ++p) {
    int idx = threadIdx.x + (p << 8);
    int i = idx >> 6, j = idx & 63;
    t[i][j] = f2bf(in[(size_t)(r0 + i) * C + c0 + j]);
  }
  __syncthreads();
#pragma unroll
  for (int p = 0; p < 16; ++p) {
    int idx = threadIdx.x + (p << 8);
    int jj = idx >> 6, ii = idx & 63;
    out[(size_t)(c0 + jj) * R + r0 + ii] = t[ii][jj];
  }
}

// ---------------------------------------------------------------------------
// concat bias: o[0:512]=a, o[512:1024]=b
// ---------------------------------------------------------------------------
__global__ __launch_bounds__(256) void catbias_k(const float* __restrict__ a,
                                                 const float* __restrict__ b,
                                                 float* __restrict__ o)
{
  int i = blockIdx.x * 256 + threadIdx.x;
  o[i] = (i < 512) ? a[i] : b[i - 512];
}

// ---------------------------------------------------------------------------
// bf16 transpose per batch: v[b][sl][ldv](+off) -> vT[b][vd][sl], 64x64 tiles
// ---------------------------------------------------------------------------
__global__ __launch_bounds__(256) void vtrans_k(const unsigned short* __restrict__ v,
                                                int ldv,
                                                unsigned short* __restrict__ vt)
{
  __shared__ unsigned short t[64][72];
  const int b  = blockIdx.z;
  const int v0 = blockIdx.x << 6;        // vd tile base
  const int s0 = blockIdx.y << 6;        // sl tile base
  const unsigned short* src = v + ((size_t)b * SLEN + s0) * ldv + v0;
#pragma unroll
  for (int p = 0; p < 2; ++p) {
    int idx = threadIdx.x + (p << 8);
    int i = idx >> 3, j8 = (idx & 7) << 3;
    *(u16x8*)&t[i][j8] = *(const u16x8*)&src[(size_t)i * ldv + j8];
  }
  __syncthreads();
  unsigned short* dst = vt + ((size_t)b * VDIM + v0) * SLEN + s0;
#pragma unroll
  for (int p = 0; p < 2; ++p) {
    int idx = threadIdx.x + (p << 8);
    int jj = idx >> 3, i8 = (idx & 7) << 3;
    u16x8 o;
#pragma unroll
    for (int e = 0; e < 8; ++e) o[e] = t[i8 + e][jj];
    *(u16x8*)&dst[(size_t)jj * SLEN + i8] = o;
  }
}

// ---------------------------------------------------------------------------
// Row softmax: read bf16 scores, write fp32 attn_w (d_out) + bf16 normalized
// in place over the score buffer. One block per row of 2048.
// ---------------------------------------------------------------------------
__global__ __launch_bounds__(256) void softmax_k(unsigned short* __restrict__ sc,
                                                 float* __restrict__ wf)
{
  __shared__ float red[8];
  const size_t base = (size_t)blockIdx.x * SLEN;
  const int t = threadIdx.x;
  u16x8 r = *(const u16x8*)(sc + base + (size_t)t * 8);
  float x[8];
#pragma unroll
  for (int e = 0; e < 8; ++e) x[e] = bf2f(r[e]);

  float m = x[0];
#pragma unroll
  for (int e = 1; e < 8; ++e) m = fmaxf(m, x[e]);
#pragma unroll
  for (int off = 32; off >= 1; off >>= 1) m = fmaxf(m, __shfl_xor(m, off));
  const int wave = t >> 6, lane = t & 63;
  if (lane == 0) red[wave] = m;
  __syncthreads();
  m = fmaxf(fmaxf(red[0], red[1]), fmaxf(red[2], red[3]));

  float sum = 0.f;
#pragma unroll
  for (int e = 0; e < 8; ++e) { x[e] = __expf(x[e] - m); sum += x[e]; }
#pragma unroll
  for (int off = 32; off >= 1; off >>= 1) sum += __shfl_xor(sum, off);
  if (lane == 0) red[4 + wave] = sum;
  __syncthreads();
  const float inv = 1.f / (red[4] + red[5] + red[6] + red[7]);

#pragma unroll
  for (int e = 0; e < 8; ++e) x[e] *= inv;
  float4 o0 = {x[0], x[1], x[2], x[3]}, o1 = {x[4], x[5], x[6], x[7]};
  *(float4*)(wf + base + (size_t)t * 8)     = o0;
  *(float4*)(wf + base + (size_t)t * 8 + 4) = o1;
  u16x8 ob;
#pragma unroll
  for (int e = 0; e < 8; ++e) ob[e] = f2bf(x[e]);
  *(u16x8*)(sc + base + (size_t)t * 8) = ob;
}

// ---------------------------------------------------------------------------
extern "C" void kernel_launch(void* const* d_in, const int* in_sizes, int n_in,
                              void* d_out, int out_size, void* d_ws, size_t ws_size,
                              hipStream_t stream)
{
  const float* q  = (const float*)d_in[0];
  const float* s  = (const float*)d_in[1];
  const int* mask = (const int*)d_in[2];
  const float* Wq = (const float*)d_in[3];
  const float* bq = (const float*)d_in[4];
  const float* Wk = (const float*)d_in[5];
  const float* bk = (const float*)d_in[6];
  const float* Wv = (const float*)d_in[7];
  const float* bv = (const float*)d_in[8];
  const float* Wo = (const float*)d_in[9];
  const float* bo = (const float*)d_in[10];

  // Workspace layout (~108.1 MB peak; lifetimes annotated, no overlaps):
  char* ws = (char*)d_ws;
  unsigned short* WqT  = (unsigned short*)(ws + ((size_t)0  << 20));  // [512][1024]   1 MB
  unsigned short* WkvT = (unsigned short*)(ws + ((size_t)1  << 20));  // [1024][1024]  2 MB (Wk|Wv)
  unsigned short* WoT  = (unsigned short*)(ws + ((size_t)3  << 20));  // [1024][512]   1 MB
  unsigned short* qbf  = (unsigned short*)(ws + ((size_t)4  << 20));  // [8192][1024] 16 MB (dead after Q-proj)
  unsigned short* sbf  = (unsigned short*)(ws + ((size_t)20 << 20));  // [16384][1024] 32 MB (dead after KV-proj)
  unsigned short* sc   = sbf;                                         // [8192][2048] bf16 scores / pw (reuse)
  unsigned short* qp   = (unsigned short*)(ws + ((size_t)52 << 20));  // [8192][512]   8 MB (dead after score)
  unsigned short* ao   = qp;                                          //  reuse for attn@V output
  unsigned short* kv   = (unsigned short*)(ws + ((size_t)60 << 20));  // [16384][1024] 32 MB (k | v fused)
  unsigned short* vT   = (unsigned short*)(ws + ((size_t)92 << 20));  // [8][512][2048] 16 MB
  float*          bkv  = (float*)         (ws + ((size_t)108 << 20)); // [1024]        4 KB

  float* attn_w = (float*)d_out;                              // [8][1024][2048]
  float* attn_o = (float*)d_out + (size_t)B_ * QL * SLEN;     // [8][1024][1024]

  // 1) activations + weights -> bf16 (weights transposed; Wk|Wv fused)
  cvt_k<<<(B_ * QL * QIN) / (256 * 8), 256, 0, stream>>>(q, qbf);
  cvt_k<<<(B_ * SLEN * KVIN) / (256 * 8), 256, 0, stream>>>(s, sbf);
  tcvt_k<<<dim3(QKD / 64, QIN / 64),   256, 0, stream>>>(Wq, QIN,  QKD,  WqT);
  tcvt_k<<<dim3(QKD / 64, KVIN / 64),  256, 0, stream>>>(Wk, KVIN, QKD,  WkvT);
  tcvt_k<<<dim3(VDIM / 64, KVIN / 64), 256, 0, stream>>>(Wv, KVIN, VDIM, WkvT + (size_t)QKD * KVIN);
  tcvt_k<<<dim3(OUTD / 64, VDIM / 64), 256, 0, stream>>>(Wo, VDIM, OUTD, WoT);
  catbias_k<<<4, 256, 0, stream>>>(bk, bv, bkv);

  // 2) projections
  gemm_bt_k<0><<<dim3(QKD / 128, (B_ * QL) / 128), 256, 0, stream>>>(
      qbf, WqT, bq, qp, QIN, QIN, QIN, QKD, 0, 0, 0, nullptr, 0.f);
  gemm_bt_k<0><<<dim3((QKD + VDIM) / 128, (B_ * SLEN) / 128), 256, 0, stream>>>(
      sbf, WkvT, bkv, kv, KVIN, KVIN, KVIN, QKD + VDIM, 0, 0, 0, nullptr, 0.f);

  // 3) v (cols 512..1023 of kv) -> vT
  vtrans_k<<<dim3(VDIM / 64, SLEN / 64, B_), 256, 0, stream>>>(kv + QKD, QKD + VDIM, vT);

  // 4) scores = qp . k^T * scale, masked -> bf16 sc
  gemm_bt_k<1><<<dim3(SLEN / 128, QL / 128, B_), 256, 0, stream>>>(
      qp, kv, nullptr, sc, QKD, QKD, QKD + VDIM, SLEN,
      (long)QL * QKD, (long)SLEN * (QKD + VDIM), (long)QL * SLEN, mask, 0.044194173824159216f);

  // 5) softmax: sc -> fp32 attn_w (d_out) + bf16 normalized in place
  softmax_k<<<B_ * QL, 256, 0, stream>>>(sc, attn_w);

  // 6) PV: pw @ vT^T -> bf16 ao
  gemm_bt_k<0><<<dim3(VDIM / 128, QL / 128, B_), 256, 0, stream>>>(
      sc, vT, nullptr, ao, SLEN, SLEN, SLEN, VDIM,
      (long)QL * SLEN, (long)VDIM * SLEN, (long)QL * VDIM, nullptr, 0.f);

  // 7) out = ao @ Wo + bo -> fp32
  gemm_bt_k<2><<<dim3(OUTD / 128, (B_ * QL) / 128), 256, 0, stream>>>(
      ao, WoT, bo, attn_o, VDIM, VDIM, VDIM, OUTD, 0, 0, 0, nullptr, 0.f);
}